// Round 1
// baseline (173.120 us; speedup 1.0000x reference)
//
#include <hip/hip_runtime.h>

// SAdapter fused kernel: one block per image (B=2048).
// All intermediates (t, z_star, P, z_hist, weights) live in LDS.
// Memory-bound: reads x (310MB), writes out (310MB).

#define NTOK 196
#define DIMD 192
#define CCH  8

__launch_bounds__(256, 4)
__global__ void sadapter_kernel(
    const float* __restrict__ x,
    const float* __restrict__ W1,
    const float* __restrict__ b1,
    const float* __restrict__ conv1_w,
    const float* __restrict__ conv1_b,
    const float* __restrict__ cdc_w,
    const float* __restrict__ wc1,
    const float* __restrict__ wc2,
    const float* __restrict__ hist_w,
    const float* __restrict__ hist_b,
    float* __restrict__ out)
{
    // LDS union layout (floats), total 9568 floats = 38272 B -> 4 blocks/CU
    __shared__ float smem[9568];
    float* W1S   = smem;          // [8][196]  phase A only
    float* TOKC  = smem + 1568;   // [28][196] phase A only (row pad 196 for conflict-free b128)
    float* ZS    = smem;          // [8][256]  phase B+ (reuses A region)
    float* PS    = smem + 2048;   // [8][256]
    float* ZH    = smem + 4096;   // [1568] in flat (c*196+hw) order
    float* TS    = smem + 7056;   // [8][256]  phases A..B
    float* HWT   = smem + 7056;   // [8][192]  phases C..D (reuses TS region)
    float* HISTB = smem + 8592;   // [192]
    float* WB    = smem + 9104;   // 464 small weights
    float* wCn = WB, *wU = WB+64, *wL = WB+128, *wR = WB+192, *wD = WB+256;
    float* wc1s = WB+320, *wc2s = WB+384;
    float* conv1bs = WB+448, *b1s = WB+456;

    const int tid = threadIdx.x;
    const int b = blockIdx.x;
    const float* xb  = x   + (size_t)b * (197*192);
    float*       outb = out + (size_t)b * (197*192);

    // ---- Phase 0: init t (zero incl. border), stage W1 + small weights ----
    for (int f = tid; f < 512; f += 256) ((float4*)TS)[f] = make_float4(0.f,0.f,0.f,0.f);
    for (int f = tid; f < 384; f += 256) {            // W1 is [8][192] contiguous
        int c = f / 48, d4 = f - c*48;
        ((float4*)W1S)[c*49 + d4] = ((const float4*)W1)[f];
    }
    if (tid < 64) {
        int o = tid >> 3, i = tid & 7;
        const float* c5 = cdc_w + o*40 + i*5;         // cdc_w (8,8,1,5)
        float k0=c5[0], k1=c5[1], k2=c5[2], k3=c5[3], k4=c5[4];
        float kd = k0+k1+k2+k3+k4;                    // kernel_diff
        wU[tid]=k0; wL[tid]=k1; wR[tid]=k3; wD[tid]=k4;
        wCn[tid] = conv1_w[tid] + k2 - 0.7f*kd;       // 1x1 + center - theta*diff
        wc1s[tid] = wc1[tid]; wc2s[tid] = wc2[tid];
    }
    if (tid < 8) { conv1bs[tid] = conv1_b[tid]; b1s[tid] = b1[tid]; }
    __syncthreads();

    // ---- Phase A: t[c][h][w] = tok @ W1^T + b1, into padded TS ----
    const float* tokg = xb + DIMD;                    // skip class token row
    for (int k = 0; k < 7; ++k) {                     // 7 chunks of 28 tokens
        const float4* src = (const float4*)(tokg + k*(28*DIMD));
        for (int f = tid; f < 1344; f += 256) {       // 28*192/4 contiguous float4
            float4 v = src[f];
            int n = f / 48, d4 = f - n*48;
            ((float4*)TOKC)[n*49 + d4] = v;           // padded row stride 196
        }
        __syncthreads();
        if (tid < 224) {                              // 28 tokens x 8 channels
            int nl = tid >> 3, c = tid & 7;
            const float4* tr = (const float4*)(TOKC + nl*196);
            const float4* wr = (const float4*)(W1S + c*196);
            float acc = b1s[c];
            #pragma unroll 8
            for (int d4 = 0; d4 < 48; ++d4) {
                float4 tv = tr[d4], wv = wr[d4];
                acc += tv.x*wv.x + tv.y*wv.y + tv.z*wv.z + tv.w*wv.w;
            }
            int n = k*28 + nl;
            int h = n / 14, w = n - h*14;
            TS[c*256 + (h+1)*16 + (w+1)] = acc;
        }
        __syncthreads();
    }

    // ---- Phase B: z_star = x1 + out_normal - theta*out_diff (padded, border 0) ----
    for (int f = tid; f < 2048; f += 256) {
        int c = f >> 8, idx = f & 255, h = idx >> 4, w = idx & 15;
        float v = 0.f;
        if (h >= 1 && h <= 14 && w >= 1 && w <= 14) {
            float acc = conv1bs[c];
            #pragma unroll
            for (int i = 0; i < 8; ++i) {
                const float* tb = TS + i*256 + h*16 + w;
                int wi = c*8 + i;
                acc += wCn[wi]*tb[0] + wU[wi]*tb[-16] + wD[wi]*tb[16]
                     + wL[wi]*tb[-1] + wR[wi]*tb[1];
            }
            v = acc;
        }
        ZS[f] = v;
    }
    __syncthreads();

    // ---- Phase C: P = exp(-(gamma*(z-mu))^2) pointwise; border = exp(0) = 1 ----
    // (also stage hist weights into the dead TS region)
    for (int f = tid; f < 1536; f += 256) {           // hist_w (192,8) -> HWT[c][d]
        int d = f >> 3, c = f & 7;
        HWT[c*DIMD + d] = hist_w[f];
    }
    if (tid < DIMD) HISTB[tid] = hist_b[tid];
    for (int f = tid; f < 2048; f += 256) {
        int c = f >> 8, idx = f & 255, h = idx >> 4, w = idx & 15;
        float v = 1.f;                                // padded nbr: g=z=m=0 -> exp(0)=1
        if (h >= 1 && h <= 14 && w >= 1 && w <= 14) {
            float zc = ZS[f];
            float mu = 0.f, ga = 0.f;
            #pragma unroll
            for (int i = 0; i < 8; ++i) {
                float zi = ZS[i*256 + idx];
                mu += wc1s[c*8+i]*zi;
                ga += wc2s[c*8+i]*zi;
            }
            float e = ga * (zc - mu);
            v = __expf(-e*e);
        }
        PS[f] = v;
    }
    __syncthreads();

    // ---- Phase C2: z_hist = 3x3 box sum of P / 9, in flat (c*196+hw) order ----
    for (int f = tid; f < 1568; f += 256) {
        int c = f / 196, hw = f - c*196;
        int h = hw / 14, w = hw - h*14;
        const float* Pr = PS + c*256 + h*16 + w;
        float s9 = Pr[0]+Pr[1]+Pr[2] + Pr[16]+Pr[17]+Pr[18] + Pr[32]+Pr[33]+Pr[34];
        ZH[f] = s9 * (1.f/9.f);
    }
    __syncthreads();

    // ---- Phase D: y = z_hist @ hist_w^T + hist_b; copy class token ----
    if (tid < 48) ((float4*)outb)[tid] = ((const float4*)xb)[tid];
    float4* outy = (float4*)(outb + DIMD);
    for (int j = tid; j < 9408; j += 256) {           // 196 * 48 float4 outputs
        int n2 = j / 48, d4 = j - n2*48;
        float4 acc = ((const float4*)HISTB)[d4];
        const float* zr = ZH + n2*8;                  // reshape trick: zh[n2*8+c2]
        #pragma unroll
        for (int c2 = 0; c2 < 8; ++c2) {
            float s = zr[c2];
            float4 hv = ((const float4*)(HWT + c2*DIMD))[d4];
            acc.x += s*hv.x; acc.y += s*hv.y; acc.z += s*hv.z; acc.w += s*hv.w;
        }
        outy[j] = acc;
    }
}

extern "C" void kernel_launch(void* const* d_in, const int* in_sizes, int n_in,
                              void* d_out, int out_size, void* d_ws, size_t ws_size,
                              hipStream_t stream)
{
    const float* x       = (const float*)d_in[0];
    const float* W1      = (const float*)d_in[1];
    const float* b1      = (const float*)d_in[2];
    const float* conv1_w = (const float*)d_in[3];
    const float* conv1_b = (const float*)d_in[4];
    const float* cdc_w   = (const float*)d_in[5];
    const float* wc1     = (const float*)d_in[6];
    const float* wc2     = (const float*)d_in[7];
    const float* hist_w  = (const float*)d_in[8];
    const float* hist_b  = (const float*)d_in[9];
    float* out = (float*)d_out;

    sadapter_kernel<<<2048, 256, 0, stream>>>(
        x, W1, b1, conv1_w, conv1_b, cdc_w, wc1, wc2, hist_w, hist_b, out);
}

// Round 2
// 166.413 us; speedup vs baseline: 1.0403x; 1.0403x over previous
//
#include <hip/hip_runtime.h>

// SAdapter fused kernel v2: one block per image (B=2048), 256 threads.
// Phase A: per-token GEMM, tokens streamed global->reg, W1 via scalar loads.
// Phase BC fused: z_star kept in registers -> mu/gamma/P directly.
// LDS 24.7 KB -> 6 blocks/CU.

#define DIMD 192

__launch_bounds__(256, 6)
__global__ void sadapter_kernel(
    const float* __restrict__ x,
    const float* __restrict__ W1,
    const float* __restrict__ b1,
    const float* __restrict__ conv1_w,
    const float* __restrict__ conv1_b,
    const float* __restrict__ cdc_w,
    const float* __restrict__ wc1,
    const float* __restrict__ wc2,
    const float* __restrict__ hist_w,
    const float* __restrict__ hist_b,
    float* __restrict__ out)
{
    // LDS: TS[8][256] (t, padded; later HWT[8][192]+HISTB[192]) | PS[8][256] | ZH[1568] | WB2[64][8]
    __shared__ float smem[6176];   // 24704 B
    float* TS    = smem;
    float* HWT   = smem;           // overlays TS after phase BC
    float* HISTB = smem + 1536;
    float* PS    = smem + 2048;
    float* ZH    = smem + 4096;
    float* WB2   = smem + 5664;

    const int tid = threadIdx.x;
    const float* xb   = x   + (size_t)blockIdx.x * (197 * DIMD);
    float*       outb = out + (size_t)blockIdx.x * (197 * DIMD);

    // ---- Phase 0: TS=0 (border must be 0), PS=1 (border must be exp(0)=1), pack weights ----
    {
        float4 z4 = make_float4(0.f, 0.f, 0.f, 0.f);
        float4 o4 = make_float4(1.f, 1.f, 1.f, 1.f);
        ((float4*)TS)[tid]       = z4;
        ((float4*)TS)[tid + 256] = z4;
        ((float4*)PS)[tid]       = o4;
        ((float4*)PS)[tid + 256] = o4;
    }
    if (tid < 64) {
        // tid = o*8+i ; cdc_w (8,8,1,5)
        const float* c5 = cdc_w + tid * 5;
        float k0 = c5[0], k1 = c5[1], k2 = c5[2], k3 = c5[3], k4 = c5[4];
        float kd = k0 + k1 + k2 + k3 + k4;
        float* wp = WB2 + tid * 8;
        wp[0] = conv1_w[tid] + k2 - 0.7f * kd;  // center: 1x1 + cdc-center - theta*diff
        wp[1] = k0;  // up
        wp[2] = k1;  // left
        wp[3] = k3;  // right
        wp[4] = k4;  // down
        wp[5] = wc1[tid];
        wp[6] = wc2[tid];
        wp[7] = 0.f;
    }
    __syncthreads();

    // ---- Phase A: t[n,c] = tok[n,:] @ W1[c,:] + b1[c]  (tokens from global, W1 via s_load) ----
    if (tid < 196) {
        const float4* rowp = (const float4*)(xb + DIMD + tid * DIMD);
        float acc[8];
        #pragma unroll
        for (int c = 0; c < 8; ++c) acc[c] = b1[c];
        #pragma unroll 2
        for (int d8 = 0; d8 < 48; d8 += 8) {
            float4 tv[8];
            #pragma unroll
            for (int u = 0; u < 8; ++u) tv[u] = rowp[d8 + u];
            #pragma unroll
            for (int u = 0; u < 8; ++u) {
                const float* wp = W1 + (d8 + u) * 4;   // uniform -> scalar loads
                #pragma unroll
                for (int c = 0; c < 8; ++c) {
                    acc[c] += tv[u].x * wp[c * DIMD + 0] + tv[u].y * wp[c * DIMD + 1]
                            + tv[u].z * wp[c * DIMD + 2] + tv[u].w * wp[c * DIMD + 3];
                }
            }
        }
        int h = tid / 14, w = tid - h * 14;
        float* tp = TS + (h + 1) * 16 + (w + 1);
        #pragma unroll
        for (int c = 0; c < 8; ++c) tp[c * 256] = acc[c];
    } else if (tid >= 208) {
        // idle lanes: copy class token through (48 float4 = 192 floats)
        ((float4*)outb)[tid - 208] = ((const float4*)xb)[tid - 208];
    }
    __syncthreads();

    // ---- Phase BC (fused): z_star in regs -> mu/gamma -> P = exp(-(g*(z-mu))^2) ----
    if (tid < 196) {
        int h = tid / 14, w = tid - h * 14;
        const float* tp = TS + (h + 1) * 16 + (w + 1);
        float zv[8];
        #pragma unroll
        for (int c = 0; c < 8; ++c) zv[c] = conv1_b[c];    // uniform -> s_load
        #pragma unroll
        for (int i = 0; i < 8; ++i) {
            float t0 = tp[i * 256];
            float tu = tp[i * 256 - 16];
            float td = tp[i * 256 + 16];
            float tl = tp[i * 256 - 1];
            float tr = tp[i * 256 + 1];
            #pragma unroll
            for (int c = 0; c < 8; ++c) {
                const float* wp = WB2 + (c * 8 + i) * 8;   // broadcast b128 + b32
                float4 wv = *(const float4*)wp;
                float wd = wp[4];
                zv[c] += wv.x * t0 + wv.y * tu + wv.z * tl + wv.w * tr + wd * td;
            }
        }
        float* pp = PS + (h + 1) * 16 + (w + 1);
        #pragma unroll
        for (int c = 0; c < 8; ++c) {
            float mu = 0.f, ga = 0.f;
            #pragma unroll
            for (int i = 0; i < 8; ++i) {
                const float* wp = WB2 + (c * 8 + i) * 8;
                mu += wp[5] * zv[i];
                ga += wp[6] * zv[i];
            }
            float e = ga * (zv[c] - mu);
            pp[c * 256] = __expf(-e * e);
        }
    }
    __syncthreads();

    // ---- Phase C2: z_hist = 3x3 box sum of P / 9 (raw [c][hw] order); stage HWT/HISTB ----
    if (tid < 196) {
        int h = tid / 14, w = tid - h * 14;
        const float* pb = PS + h * 16 + w;   // top-left of 3x3 window in padded coords
        #pragma unroll
        for (int c = 0; c < 8; ++c) {
            const float* pr = pb + c * 256;
            float s9 = pr[0] + pr[1] + pr[2]
                     + pr[16] + pr[17] + pr[18]
                     + pr[32] + pr[33] + pr[34];
            ZH[c * 196 + tid] = s9 * (1.f / 9.f);
        }
    } else {
        // threads 196..255: stage hist_w transposed -> HWT[c][d], and HISTB
        for (int f = tid - 196; f < 384; f += 60) {
            float4 v = ((const float4*)hist_w)[f];   // hist_w (192,8): flat = d*8+c
            int d = f >> 1, c0 = (f & 1) * 4;
            HWT[(c0 + 0) * DIMD + d] = v.x;
            HWT[(c0 + 1) * DIMD + d] = v.y;
            HWT[(c0 + 2) * DIMD + d] = v.z;
            HWT[(c0 + 3) * DIMD + d] = v.w;
        }
        for (int f = tid - 196; f < 48; f += 60)
            ((float4*)HISTB)[f] = ((const float4*)hist_b)[f];
    }
    __syncthreads();

    // ---- Phase D: y = z_hist @ hist_w^T + hist_b (division-free rolling index) ----
    {
        float4* outy = (float4*)(outb + DIMD);
        int d4 = tid % 48;
        int n2 = tid / 48;
        while (n2 < 196) {
            float4 a = ((const float4*)HISTB)[d4];
            const float* zr = ZH + n2 * 8;   // reshape trick: zh flat [n2*8+c2]
            #pragma unroll
            for (int c2 = 0; c2 < 8; ++c2) {
                float s = zr[c2];
                float4 hv = ((const float4*)(HWT + c2 * DIMD))[d4];
                a.x += s * hv.x; a.y += s * hv.y; a.z += s * hv.z; a.w += s * hv.w;
            }
            outy[n2 * 48 + d4] = a;
            n2 += 5; d4 += 16;
            if (d4 >= 48) { d4 -= 48; n2 += 1; }
        }
    }
}

extern "C" void kernel_launch(void* const* d_in, const int* in_sizes, int n_in,
                              void* d_out, int out_size, void* d_ws, size_t ws_size,
                              hipStream_t stream)
{
    const float* x       = (const float*)d_in[0];
    const float* W1      = (const float*)d_in[1];
    const float* b1      = (const float*)d_in[2];
    const float* conv1_w = (const float*)d_in[3];
    const float* conv1_b = (const float*)d_in[4];
    const float* cdc_w   = (const float*)d_in[5];
    const float* wc1     = (const float*)d_in[6];
    const float* wc2     = (const float*)d_in[7];
    const float* hist_w  = (const float*)d_in[8];
    const float* hist_b  = (const float*)d_in[9];
    float* out = (float*)d_out;

    sadapter_kernel<<<2048, 256, 0, stream>>>(
        x, W1, b1, conv1_w, conv1_b, cdc_w, wc1, wc2, hist_w, hist_b, out);
}